// Round 5
// baseline (155.161 us; speedup 1.0000x reference)
//
#include <hip/hip_runtime.h>

#define NFFT 3072
#define THREADS 256
#define HOP 192
#define HALF 1536
#define TFRAMES 1000
#define OUTLEN 191808
#define NBANDS 128
#define PI_F 3.14159265358979323846f
#define SEGLEN 3264               // 3072 + HOP: two merged frames' OLA span
#define NSEG 500                  // TFRAMES/2 segments per batch

__device__ __forceinline__ float2 cadd(float2 a,float2 b){return make_float2(a.x+b.x,a.y+b.y);}
__device__ __forceinline__ float2 csub(float2 a,float2 b){return make_float2(a.x-b.x,a.y-b.y);}
__device__ __forceinline__ float2 cmul(float2 a,float2 b){
    return make_float2(fmaf(a.x,b.x,-a.y*b.y), fmaf(a.x,b.y,a.y*b.x));
}
__device__ __forceinline__ float2 cmuln_i(float2 a){return make_float2(a.y,-a.x);}  // a * (-i)
__device__ __forceinline__ float2 cneg(float2 a){return make_float2(-a.x,-a.y);}

// LDS padding: +1 float2 every 16 (128B) to break mod-16 bank aliasing
__device__ __forceinline__ int IDX(int i){ return i + (i>>4); }

__device__ __forceinline__ void dft4(float2 a0,float2 a1,float2 a2,float2 a3,
                                     float2&y0,float2&y1,float2&y2,float2&y3){
    float2 e0=cadd(a0,a2), e1=csub(a0,a2), o0=cadd(a1,a3), o1=csub(a1,a3);
    y0=cadd(e0,o0); y2=csub(e0,o0);
    float2 io=make_float2(-o1.y,o1.x);   // i*o1
    y1=csub(e1,io); y3=cadd(e1,io);
}
__device__ __forceinline__ void dft3(float2 a0,float2 a1,float2 a2,
                                     float2&y0,float2&y1,float2&y2){
    float2 s=cadd(a1,a2), d=csub(a1,a2);
    y0=cadd(a0,s);
    float2 t=make_float2(a0.x-0.5f*s.x, a0.y-0.5f*s.y);
    const float S3=0.86602540378443864676f;
    float2 id=make_float2(S3*d.y,-S3*d.x);   // -i*S3*d
    y1=cadd(t,id); y2=csub(t,id);
}

// 12-point DFT: o[j] = sum_l a[l] w12^{lj}.  12 = 4x3
__device__ __forceinline__ void dft12(float2 a[12], float2 o[12]){
    float2 u[3][4];
    #pragma unroll
    for(int n2=0;n2<3;++n2)
        dft4(a[n2],a[3+n2],a[6+n2],a[9+n2],u[n2][0],u[n2][1],u[n2][2],u[n2][3]);
    const float2 W1=make_float2( 0.86602540378443865f,-0.5f);
    const float2 W2=make_float2( 0.5f,-0.86602540378443865f);
    const float2 W4=make_float2(-0.5f,-0.86602540378443865f);
    u[1][1]=cmul(u[1][1],W1); u[1][2]=cmul(u[1][2],W2); u[1][3]=cmuln_i(u[1][3]);
    u[2][1]=cmul(u[2][1],W2); u[2][2]=cmul(u[2][2],W4); u[2][3]=cneg(u[2][3]);
    #pragma unroll
    for(int k1=0;k1<4;++k1)
        dft3(u[0][k1],u[1][k1],u[2][k1], o[k1],o[k1+4],o[k1+8]);
}

// 16-point DFT: 16 = 4x4
__device__ __forceinline__ void dft16(float2 a[16], float2 o[16]){
    float2 u[4][4];
    #pragma unroll
    for(int n2=0;n2<4;++n2)
        dft4(a[n2],a[4+n2],a[8+n2],a[12+n2],u[n2][0],u[n2][1],u[n2][2],u[n2][3]);
    const float C16=0.92387953251128674f, S16=0.38268343236508977f, R2=0.70710678118654752f;
    const float2 W1=make_float2( C16,-S16), W2=make_float2( R2,-R2), W3=make_float2( S16,-C16);
    const float2 W6=make_float2(-R2,-R2),  W9=make_float2(-C16, S16);
    u[1][1]=cmul(u[1][1],W1); u[1][2]=cmul(u[1][2],W2);   u[1][3]=cmul(u[1][3],W3);
    u[2][1]=cmul(u[2][1],W2); u[2][2]=cmuln_i(u[2][2]);   u[2][3]=cmul(u[2][3],W6);
    u[3][1]=cmul(u[3][1],W3); u[3][2]=cmul(u[3][2],W6);   u[3][3]=cmul(u[3][3],W9);
    #pragma unroll
    for(int k1=0;k1<4;++k1)
        dft4(u[0][k1],u[1][k1],u[2][k1],u[3][k1], o[k1],o[k1+4],o[k1+8],o[k1+12]);
}

// multiply o[j] *= w^j, w = e^{i*ang};  power tree
template<int R>
__device__ __forceinline__ void twiddle_pows(float2* o, float ang){
    float s,c; __sincosf(ang,&s,&c);
    float2 w1=make_float2(c,s);
    float2 w2=cmul(w1,w1);
    float2 w3=cmul(w2,w1);
    float2 w4=cmul(w2,w2);
    o[1]=cmul(o[1],w1); o[2]=cmul(o[2],w2); o[3]=cmul(o[3],w3);
    float2 w8=cmul(w4,w4);
    float2 w5=cmul(w4,w1), w6=cmul(w4,w2), w7=cmul(w4,w3);
    o[4]=cmul(o[4],w4); o[5]=cmul(o[5],w5); o[6]=cmul(o[6],w6); o[7]=cmul(o[7],w7);
    float2 w9=cmul(w8,w1), w10=cmul(w8,w2), w11=cmul(w8,w3);
    o[8]=cmul(o[8],w8); o[9]=cmul(o[9],w9); o[10]=cmul(o[10],w10); o[11]=cmul(o[11],w11);
    if constexpr (R>12){
        float2 w12=cmul(w8,w4), w13=cmul(w8,w5), w14=cmul(w8,w6), w15=cmul(w8,w7);
        o[12]=cmul(o[12],w12); o[13]=cmul(o[13],w13); o[14]=cmul(o[14],w14); o[15]=cmul(o[15],w15);
    }
}

// Stockham stage B: (NN=256, S=12, R=16)
__device__ __forceinline__ void stageB(float2* A, int tid){
    const bool act = tid < 192;
    float2 o[16];
    int q=0,p=0;
    if(act){
        q = tid % 12; p = tid / 12;
        float2 a[16];
        int ib = IDX(q + 12*p);            // linear stride 192 -> padded 204
        #pragma unroll
        for(int l=0;l<16;++l) a[l] = A[ib + 204*l];
        dft16(a,o);
        twiddle_pows<16>(o, -2.0f*PI_F*(float)p*(1.0f/256.0f));
    }
    __syncthreads();
    if(act){
        #pragma unroll
        for(int j=0;j<16;++j) A[IDX(q + 192*p + 12*j)] = o[j];
    }
    __syncthreads();
}

// K1: two frames per block -> FFT -> filter -> IFFT -> window -> register-merged
// OLA segment (3264 samples).  USE_WS: non-atomic contiguous store to ws;
// fallback (!USE_WS): device atomics straight into out (R4 behavior).
template<bool USE_WS>
__global__ __launch_bounds__(THREADS,4)
void filtered_noise_kernel(const float* __restrict__ fb,
                           const float* __restrict__ noise,
                           float* __restrict__ ws,
                           float* __restrict__ out)
{
    __shared__ float2 A[NFFT + NFFT/16];   // 3264 float2 = 26112 B
    __shared__ float gf[2*NBANDS];

    const int tid = threadIdx.x;
    // XCD swizzle: batch = blockIdx&7 pins each batch's noise re-reads (17x
    // overlap) to one XCD's L2.
    const int b   = blockIdx.x & 7;
    const int tp  = blockIdx.x >> 3;
    const int t0  = 2*tp;
    const float* nz = noise + (size_t)b * OUTLEN;
    const int base0 = t0*HOP - HALF;

    // filter gains: gf[0..127] frame t0, gf[128..255] frame t0+1
    gf[tid] = fb[((size_t)b*NBANDS + (tid & 127))*TFRAMES + t0 + (tid >> 7)];

    // ---- Phase 1: fwd stage A (NN=3072,S=1,R=12), global -> LDS ----
    {
        float2 a[12], o[12];
        #pragma unroll
        for(int l=0;l<12;++l){
            int i0 = base0 + tid + 256*l;
            float x0 = (i0 >= 0 && i0 < OUTLEN) ? nz[i0] : 0.0f;
            int i1 = i0 + HOP;
            float x1 = (i1 >= 0 && i1 < OUTLEN) ? nz[i1] : 0.0f;
            a[l] = make_float2(x0, x1);
        }
        dft12(a,o);
        twiddle_pows<12>(o, -2.0f*PI_F*(float)tid*(1.0f/3072.0f));
        #pragma unroll
        for(int j=0;j<12;++j) A[IDX(12*tid + j)] = o[j];
    }
    __syncthreads();

    // ---- Phase 2: fwd stage B ----
    stageB(A, tid);

    // ---- Phase 3: fwd stage C (NN=16,S=192,R=16, no twiddle), in-place ----
    {
        const bool act = tid < 192;
        float2 o[16];
        if(act){
            float2 a[16];
            int ib = IDX(tid);
            #pragma unroll
            for(int l=0;l<16;++l) a[l] = A[ib + 204*l];
            dft16(a,o);
        }
        __syncthreads();
        if(act){
            int ib = IDX(tid);
            #pragma unroll
            for(int j=0;j<16;++j) A[ib + 204*j] = o[j];
        }
        __syncthreads();
    }

    // ---- Phase 4: spectral multiply fused into inv stage A (R=12) ----
    // Z natural order: Z[k] at A[IDX(k)]; linear stride 256 -> padded 272.
    // W'[k] = conj(W[k]) = a_k*conj(Z[k]) + b_k*Z[N-k]
    {
        const int p = tid;
        float2 z[12], zm[12];
        {
            int ib = IDX(p);
            #pragma unroll
            for(int l=0;l<12;++l) z[l] = A[ib + 272*l];     // Z[p + 256*l]
        }
        {
            int pm = (p==0) ? 0 : (256 - p);
            int ib = IDX(pm);
            #pragma unroll
            for(int l=0;l<12;++l) zm[l] = A[ib + 272*l];    // Z[pm + 256*l]
        }
        float2 w[12];
        #pragma unroll
        for(int l=0;l<12;++l){
            int k = p + 256*l;
            int j = (k <= HALF) ? k : (NFFT - k);
            float aa = 0.0f, bb = 0.0f;
            if(j){
                int band = (j-1)/12;
                float Gx = gf[band], Gy = gf[NBANDS + band];
                aa = 0.5f*(Gx+Gy); bb = 0.5f*(Gx-Gy);
            }
            float2 Zm = (p==0) ? ((l==0) ? z[0] : z[12-l]) : zm[11-l];
            w[l] = make_float2( fmaf(aa, z[l].x,  bb*Zm.x),
                                fmaf(-aa, z[l].y, bb*Zm.y) );
        }
        float2 o[12];
        dft12(w,o);
        twiddle_pows<12>(o, -2.0f*PI_F*(float)p*(1.0f/3072.0f));
        __syncthreads();                        // all reads done before writes
        #pragma unroll
        for(int j=0;j<12;++j) A[IDX(12*p + j)] = o[j];
        __syncthreads();
    }

    // ---- Phase 5: inv stage B ----
    stageB(A, tid);

    // ---- Phase 6: inv stage C + window + register OLA-merge + store ----
    // Frame t0 local sample n lands at combined c = n; frame t0+1 local sample
    // n lands at c = n + 192.  For c = tid + 192*j both contributions live in
    // THIS thread: o[j].x (vx) and o[j-1].y (vy). No LDS pass, no barrier.
    {
        const bool act = tid < 192;
        if(act){
            float2 a[16], o[16];
            int ib = IDX(tid);
            #pragma unroll
            for(int l=0;l<16;++l) a[l] = A[ib + 204*l];
            dft16(a,o);
            const float invN = 1.0f/(float)NFFT;
            float prev_vy = 0.0f;
            float* seg = USE_WS ? (ws + (size_t)(b*NSEG + tp)*SEGLEN) : nullptr;
            float* outb = USE_WS ? nullptr : (out + (size_t)b*OUTLEN);
            #pragma unroll
            for(int j=0;j<17;++j){
                int c = tid + 192*j;
                float val = prev_vy;
                if (j < 16){
                    float h = 0.5f - 0.5f*__cosf(2.0f*PI_F*(float)c*(1.0f/3071.0f));
                    float s = invN*h;
                    val    += o[j].x * s;       // frame t0 at local index c
                    prev_vy = -o[j].y * s;      // frame t0+1, lands at c+192
                }
                if (USE_WS){
                    seg[c] = val;
                } else {
                    int p0 = base0 + c;
                    if (p0 >= 0 && p0 < OUTLEN) atomicAdd(&outb[p0], val);
                }
            }
        }
    }
}

// K2: pure overlap-add reduction.  out[b][n] = sum of the <=9 segments covering n.
// Segment tp covers out range [384*tp-1536, +3264); c = n + 1536 - 384*tp.
__global__ __launch_bounds__(256)
void ola_reduce_kernel(const float* __restrict__ ws, float* __restrict__ out)
{
    const int n = blockIdx.x*256 + threadIdx.x;
    const int b = blockIdx.y;
    if (n >= OUTLEN) return;
    int tp1 = (n + 1536) / 384;            if (tp1 > NSEG-1) tp1 = NSEG-1;
    int tp0 = (n > 1727) ? (n - 1344) / 384 : 0;   // ceil((n-1727)/384)
    const float* wb = ws + (size_t)b*NSEG*SEGLEN;
    float s = 0.0f;
    #pragma unroll
    for (int i = 0; i < 9; ++i){
        int tp = tp0 + i;
        if (tp <= tp1)
            s += wb[tp*SEGLEN + (n + 1536 - 384*tp)];
    }
    out[(size_t)b*OUTLEN + n] = s;
}

extern "C" void kernel_launch(void* const* d_in, const int* in_sizes, int n_in,
                              void* d_out, int out_size, void* d_ws, size_t ws_size,
                              hipStream_t stream)
{
    const float* fb    = (const float*)d_in[0];   // (8,1,128,1000) f32
    const float* noise = (const float*)d_in[1];   // (8,1,191808)   f32
    float* out = (float*)d_out;                   // (8,1,191808)   f32

    const int B = in_sizes[1] / OUTLEN;           // 8
    const size_t need = (size_t)B * NSEG * SEGLEN * sizeof(float);  // 52.2 MB

    dim3 grid1(B * NSEG);                         // 4000 workgroups, 2 frames each

    if (ws_size >= need){
        filtered_noise_kernel<true><<<grid1, THREADS, 0, stream>>>(
            fb, noise, (float*)d_ws, out);
        dim3 grid2((OUTLEN + 255)/256, B);
        ola_reduce_kernel<<<grid2, 256, 0, stream>>>((float*)d_ws, out);
    } else {
        hipMemsetAsync(out, 0, (size_t)out_size * sizeof(float), stream);
        filtered_noise_kernel<false><<<grid1, THREADS, 0, stream>>>(
            fb, noise, nullptr, out);
    }
}